// Round 5
// baseline (2309.383 us; speedup 1.0000x reference)
//
#include <hip/hip_runtime.h>

// Problem constants (from reference)
constexpr int B_   = 4;
constexpr int N_   = 16384;
constexpr int NOUT = 1170;   // 16384 // 14
constexpr int D_   = 128;
constexpr int O_   = 256;

typedef float f32x2 __attribute__((ext_vector_type(2)));
typedef unsigned long long u64;

// DPP-based wave max (validated R4: absmax=0). After the 6-op chain lane 63
// holds the 64-lane max (update_dpp keeps old value where pattern has no src).
template <int CTRL>
__device__ __forceinline__ float dpp_fmax(float x) {
  int yi = __builtin_amdgcn_update_dpp(__float_as_int(x), __float_as_int(x),
                                       CTRL, 0xF, 0xF, false);
  return fmaxf(x, __int_as_float(yi));
}
__device__ __forceinline__ float wave_fmax(float v) {
  v = dpp_fmax<0xB1>(v);   // quad_perm xor1
  v = dpp_fmax<0x4E>(v);   // quad_perm xor2
  v = dpp_fmax<0x141>(v);  // row_half_mirror
  v = dpp_fmax<0x140>(v);  // row_mirror
  v = dpp_fmax<0x142>(v);  // row_bcast15
  v = dpp_fmax<0x143>(v);  // row_bcast31
  return __int_as_float(__builtin_amdgcn_readlane(__float_as_int(v), 63));
}
__device__ __forceinline__ u64 umax64(u64 a, u64 b) { return a > b ? a : b; }

// ---------------- spatial sort (one-time) ----------------
// Counting sort by 12-bit Morton code (16^3 grid over [-5,5]^3; Gaussian
// outliers clamp to edge cells — affects locality only, never correctness).
constexpr int NCELL = 4096;

__device__ __forceinline__ unsigned exp3(unsigned v) {  // 4 bits -> 0,3,6,9
  return (v & 1u) | ((v & 2u) << 2) | ((v & 4u) << 4) | ((v & 8u) << 6);
}
__device__ __forceinline__ int quant16(float v) {
  int q = (int)((v + 5.0f) * 1.6f);
  return q < 0 ? 0 : (q > 15 ? 15 : q);
}

__global__ __launch_bounds__(1024)
void sort_kernel(const float* __restrict__ pcd_x,
                 float* __restrict__ sx, float* __restrict__ sy,
                 float* __restrict__ sz, int* __restrict__ so) {
  const int b = blockIdx.x, t = threadIdx.x;
  const float* __restrict__ P = pcd_x + (size_t)b * N_ * 3;
  float* SX = sx + (size_t)b * N_;
  float* SY = sy + (size_t)b * N_;
  float* SZ = sz + (size_t)b * N_;
  int*   SO = so + (size_t)b * N_;

  __shared__ unsigned hist[NCELL];
  __shared__ unsigned wtot[16];
#pragma unroll
  for (int i = 0; i < NCELL / 1024; ++i) hist[t + i * 1024] = 0;
  __syncthreads();

  unsigned code[16];
#pragma unroll
  for (int j = 0; j < 16; ++j) {
    const int p = t + j * 1024;
    const float x = P[p * 3 + 0], y = P[p * 3 + 1], z = P[p * 3 + 2];
    code[j] = exp3(quant16(x)) | (exp3(quant16(y)) << 1) | (exp3(quant16(z)) << 2);
    atomicAdd(&hist[code[j]], 1u);
  }
  __syncthreads();

  // exclusive prefix sum over 4096 (4 per thread + wave scan + wave totals)
  unsigned h[4], sum = 0;
#pragma unroll
  for (int i = 0; i < 4; ++i) { h[i] = hist[t * 4 + i]; sum += h[i]; }
  unsigned sc = sum;
#pragma unroll
  for (int d = 1; d < 64; d <<= 1) {
    const unsigned v = __shfl_up(sc, d, 64);
    if ((t & 63) >= d) sc += v;
  }
  if ((t & 63) == 63) wtot[t >> 6] = sc;
  __syncthreads();
  unsigned woff = 0;
  for (int w = 0; w < (t >> 6); ++w) woff += wtot[w];
  const unsigned excl = woff + sc - sum;
  hist[t * 4 + 0] = excl;
  hist[t * 4 + 1] = excl + h[0];
  hist[t * 4 + 2] = excl + h[0] + h[1];
  hist[t * 4 + 3] = excl + h[0] + h[1] + h[2];
  __syncthreads();

#pragma unroll
  for (int j = 0; j < 16; ++j) {
    const int p = t + j * 1024;
    const unsigned pos = atomicAdd(&hist[code[j]], 1u);
    SX[pos] = P[p * 3 + 0];
    SY[pos] = P[p * 3 + 1];
    SZ[pos] = P[p * 3 + 2];
    SO[pos] = p;
  }
}

// ---------------- sparse FPS ----------------
// Thread t owns sorted points [16t,16t+16): register bbox + running
// (thr_max, first-orig-idx, sorted-pos). Skip iff box_dist > thr_max*(1+4e-6)
// (margin covers <=5 f32 roundings: skipped points provably have d_new >= dm,
// so dm AND the stored argmax stay bit-exact). Dirty threads recompute with
// the exact np order ((dx^2+dy^2)+dz^2, contract off) + min-orig-index tie
// scan. All reduce tiers tie-break to min orig index == np first-max.
__global__ __launch_bounds__(1024)
void fps_fast_kernel(const float* __restrict__ pcd_x,
                     const float* __restrict__ sx, const float* __restrict__ sy,
                     const float* __restrict__ sz, const int* __restrict__ so,
                     int* __restrict__ sel, float* __restrict__ out_c) {
  const int b = blockIdx.x, t = threadIdx.x;
  const float* __restrict__ SX = sx + (size_t)b * N_;
  const float* __restrict__ SY = sy + (size_t)b * N_;
  const float* __restrict__ SZ = sz + (size_t)b * N_;
  const int*   __restrict__ SO = so + (size_t)b * N_;
  const int base = t * 16;

  float xs[16], ys[16], zs[16], dmv[16];
  int oi[16];
#pragma unroll
  for (int j = 0; j < 16; ++j) {
    xs[j] = SX[base + j]; ys[j] = SY[base + j]; zs[j] = SZ[base + j];
    oi[j] = SO[base + j]; dmv[j] = 1e10f;
  }
  float lox = xs[0], hix = xs[0], loy = ys[0], hiy = ys[0], loz = zs[0], hiz = zs[0];
#pragma unroll
  for (int j = 1; j < 16; ++j) {
    lox = fminf(lox, xs[j]); hix = fmaxf(hix, xs[j]);
    loy = fminf(loy, ys[j]); hiy = fmaxf(hiy, ys[j]);
    loz = fminf(loz, zs[j]); hiz = fmaxf(hiz, zs[j]);
  }
  float thr_max = 1e10f;   // forces every thread dirty at step 1
  int thr_oi = 0, thr_pos = base;

  __shared__ u64 s_key[2][16];

  float lx = pcd_x[(size_t)b * N_ * 3 + 0];
  float ly = pcd_x[(size_t)b * N_ * 3 + 1];
  float lz = pcd_x[(size_t)b * N_ * 3 + 2];
  if (t == 0) {
    sel[b * NOUT + 0] = 0;
    out_c[((size_t)b * NOUT + 0) * 3 + 0] = lx;
    out_c[((size_t)b * NOUT + 0) * 3 + 1] = ly;
    out_c[((size_t)b * NOUT + 0) * 3 + 2] = lz;
  }

  for (int step = 1; step < NOUT; ++step) {
    const int par = step & 1;
    // f32 box distance (conservative with margin; FMA allowed, bound covers it)
    const float bx = fmaxf(0.f, fmaxf(lox - lx, lx - hix));
    const float by = fmaxf(0.f, fmaxf(loy - ly, ly - hiy));
    const float bz = fmaxf(0.f, fmaxf(loz - lz, lz - hiz));
    const float bb = bx * bx + by * by + bz * bz;

    if (!(bb > thr_max * (1.0f + 4e-6f))) {  // dirty: must update
      float nm = -1.0f;
      {
#pragma clang fp contract(off)
#pragma unroll
        for (int j = 0; j < 16; ++j) {
          const float dx = xs[j] - lx;
          const float dy = ys[j] - ly;
          const float dz = zs[j] - lz;
          const float s  = (dx * dx + dy * dy) + dz * dz;  // EXACT np order
          const float nd = fminf(dmv[j], s);
          dmv[j] = nd;
          nm = fmaxf(nm, nd);
        }
      }
      thr_max = nm;
      int boi = 0x7fffffff, bj = 0;
#pragma unroll
      for (int j = 0; j < 16; ++j) {
        if (dmv[j] == nm && oi[j] < boi) { boi = oi[j]; bj = j; }
      }
      thr_oi = boi; thr_pos = base + bj;
    }

    // wave reduce: value max, then exact min-orig-idx among achievers
    const float wmax = wave_fmax(thr_max);
    const u64 mask = __ballot(thr_max == wmax);
    int oidx, pos;
    if (__popcll(mask) == 1) {
      const int l = __builtin_ctzll(mask);
      oidx = __builtin_amdgcn_readlane(thr_oi, l);
      pos  = __builtin_amdgcn_readlane(thr_pos, l);
    } else {  // measure-zero tie path, wave-uniform loop
      oidx = 0x7fffffff; pos = 0;
      u64 m = mask;
      while (m) {
        const int l = __builtin_ctzll(m); m &= m - 1;
        const int o = __builtin_amdgcn_readlane(thr_oi, l);
        const int p = __builtin_amdgcn_readlane(thr_pos, l);
        if (o < oidx) { oidx = o; pos = p; }
      }
    }

    // packed key: value(32b)<<28 | (16383-oidx)<<14 | pos  (60 bits)
    if ((t & 63) == 0)
      s_key[par][t >> 6] = ((u64)__float_as_uint(wmax) << 28) |
                           ((u64)(unsigned)((~oidx) & 0x3FFF) << 14) |
                           (u64)(unsigned)pos;
    __syncthreads();  // single barrier per step (double-buffered s_key)

    const ulonglong2* kp = reinterpret_cast<const ulonglong2*>(&s_key[par][0]);
    u64 m8[8];
#pragma unroll
    for (int i = 0; i < 8; ++i) { const ulonglong2 v = kp[i]; m8[i] = umax64(v.x, v.y); }
    const u64 kmax = umax64(umax64(umax64(m8[0], m8[1]), umax64(m8[2], m8[3])),
                            umax64(umax64(m8[4], m8[5]), umax64(m8[6], m8[7])));

    int wpos = (int)((unsigned)kmax & 0x3FFFu);
    int woi  = 16383 - (int)((unsigned)(kmax >> 14) & 0x3FFFu);
    wpos = __builtin_amdgcn_readfirstlane(wpos);
    woi  = __builtin_amdgcn_readfirstlane(woi);

    lx = SX[wpos]; ly = SY[wpos]; lz = SZ[wpos];
    if (t == 0) {
      sel[b * NOUT + step] = woi;
      out_c[((size_t)b * NOUT + step) * 3 + 0] = lx;
      out_c[((size_t)b * NOUT + step) * 3 + 1] = ly;
      out_c[((size_t)b * NOUT + step) * 3 + 2] = lz;
    }
  }
}

// ---------------- brute-force FPS fallback (R4, passed) ----------------
constexpr int TPB_FPS = 1024;
constexpr int PPT   = N_ / TPB_FPS;  // 16
constexpr int NPAIR = PPT / 2;       // 8
constexpr int NW    = TPB_FPS / 64;  // 16

__global__ __launch_bounds__(TPB_FPS)
void fps_brute_kernel(const float* __restrict__ pcd_x,
                      int* __restrict__ sel, float* __restrict__ out_c) {
  const int b = blockIdx.x, t = threadIdx.x;
  const float* __restrict__ P = pcd_x + (size_t)b * N_ * 3;
  const int base = t * PPT;
  f32x2 x[NPAIR], y[NPAIR], z[NPAIR], dm[NPAIR];
#pragma unroll
  for (int k = 0; k < NPAIR; ++k) {
    const int p0 = base + 2 * k;
    x[k]  = f32x2{P[p0 * 3 + 0], P[p0 * 3 + 3]};
    y[k]  = f32x2{P[p0 * 3 + 1], P[p0 * 3 + 4]};
    z[k]  = f32x2{P[p0 * 3 + 2], P[p0 * 3 + 5]};
    dm[k] = f32x2{1e10f, 1e10f};
  }
  __shared__ u64 s_key[2][NW];
  float lx = P[0], ly = P[1], lz = P[2];
  if (t == 0) {
    sel[b * NOUT + 0] = 0;
    out_c[((size_t)b * NOUT + 0) * 3 + 0] = lx;
    out_c[((size_t)b * NOUT + 0) * 3 + 1] = ly;
    out_c[((size_t)b * NOUT + 0) * 3 + 2] = lz;
  }
  for (int step = 1; step < NOUT; ++step) {
    const int par = step & 1;
    const f32x2 lxx = {lx, lx}, lyy = {ly, ly}, lzz = {lz, lz};
    f32x2 bv2 = {-1.0f, -1.0f};
    {
#pragma clang fp contract(off)
#pragma unroll
      for (int k = 0; k < NPAIR; ++k) {
        const f32x2 dx = x[k] - lxx, dy = y[k] - lyy, dz = z[k] - lzz;
        const f32x2 s = (dx * dx + dy * dy) + dz * dz;
        f32x2 nd; nd.x = fminf(dm[k].x, s.x); nd.y = fminf(dm[k].y, s.y);
        dm[k] = nd;
        bv2.x = fmaxf(bv2.x, nd.x); bv2.y = fmaxf(bv2.y, nd.y);
      }
    }
    const float bv = fmaxf(bv2.x, bv2.y);
    const float wmax = wave_fmax(bv);
    int bi = 0;
#pragma unroll
    for (int k = NPAIR - 1; k >= 0; --k) {
      if (dm[k].y == bv) bi = base + 2 * k + 1;
      if (dm[k].x == bv) bi = base + 2 * k;
    }
    const u64 mask = __ballot(bv == wmax);
    const int flane = __builtin_ctzll(mask);
    const int idx_w = __builtin_amdgcn_readlane(bi, flane);
    const u64 key = ((u64)__float_as_uint(wmax) << 32) | (unsigned)(~idx_w);
    if ((t & 63) == 0) s_key[par][t >> 6] = key;
    __syncthreads();
    const ulonglong2* kp = reinterpret_cast<const ulonglong2*>(&s_key[par][0]);
    u64 m8[8];
#pragma unroll
    for (int i = 0; i < 8; ++i) { const ulonglong2 v = kp[i]; m8[i] = umax64(v.x, v.y); }
    const u64 kmax = umax64(umax64(umax64(m8[0], m8[1]), umax64(m8[2], m8[3])),
                            umax64(umax64(m8[4], m8[5]), umax64(m8[6], m8[7])));
    int ri = (int)(~(unsigned)kmax);
    ri = __builtin_amdgcn_readfirstlane(ri);
    lx = P[ri * 3 + 0]; ly = P[ri * 3 + 1]; lz = P[ri * 3 + 2];
    if (t == 0) {
      sel[b * NOUT + step] = ri;
      out_c[((size_t)b * NOUT + step) * 3 + 0] = lx;
      out_c[((size_t)b * NOUT + step) * 3 + 1] = ly;
      out_c[((size_t)b * NOUT + step) * 3 + 2] = lz;
    }
  }
}

// ---------------- projection + gathers ----------------
constexpr int TPB_PROJ = 256;
constexpr int RPB = 4;

__global__ __launch_bounds__(TPB_PROJ)
void proj_kernel(const float* __restrict__ tgt,
                 const float* __restrict__ pcd_v,
                 const float* __restrict__ W,
                 const float* __restrict__ bias,
                 const int* __restrict__ sel,
                 float* __restrict__ out_f,
                 float* __restrict__ out_v) {
  const int t = threadIdx.x;
  const int row0 = blockIdx.x * RPB;
  __shared__ float sA[RPB * D_];
  __shared__ int   sIdx[RPB];
  if (t < RPB) {
    const int row = row0 + t;
    const int b = row / NOUT;
    sIdx[t] = b * N_ + sel[row];
  }
  __syncthreads();
#pragma unroll
  for (int l = 0; l < RPB * D_ / TPB_PROJ; ++l) {
    const int e = t + l * TPB_PROJ;
    const int r = e >> 7, k = e & (D_ - 1);
    sA[e] = tgt[(size_t)sIdx[r] * D_ + k];
  }
  __syncthreads();
  float acc0 = 0.f, acc1 = 0.f, acc2 = 0.f, acc3 = 0.f;
#pragma unroll 8
  for (int k = 0; k < D_; ++k) {
    const float w = W[k * O_ + t];
    acc0 = fmaf(sA[0 * D_ + k], w, acc0);
    acc1 = fmaf(sA[1 * D_ + k], w, acc1);
    acc2 = fmaf(sA[2 * D_ + k], w, acc2);
    acc3 = fmaf(sA[3 * D_ + k], w, acc3);
  }
  const float bb = bias[t];
  out_f[(size_t)(row0 + 0) * O_ + t] = acc0 + bb;
  out_f[(size_t)(row0 + 1) * O_ + t] = acc1 + bb;
  out_f[(size_t)(row0 + 2) * O_ + t] = acc2 + bb;
  out_f[(size_t)(row0 + 3) * O_ + t] = acc3 + bb;
  if (t < RPB * 9) {
    const int r = t / 9, e = t - r * 9;
    out_v[(size_t)(row0 + r) * 9 + e] = pcd_v[(size_t)sIdx[r] * 9 + e];
  }
}

extern "C" void kernel_launch(void* const* d_in, const int* in_sizes, int n_in,
                              void* d_out, int out_size, void* d_ws, size_t ws_size,
                              hipStream_t stream) {
  const float* tgt   = (const float*)d_in[0];
  const float* pcd_x = (const float*)d_in[1];
  const float* pcd_v = (const float*)d_in[2];
  const float* W     = (const float*)d_in[3];
  const float* bias  = (const float*)d_in[4];

  float* out   = (float*)d_out;
  float* out_f = out;
  float* out_c = out + (size_t)B_ * NOUT * O_;
  float* out_v = out_c + (size_t)B_ * NOUT * 3;

  const size_t need = (size_t)4 * B_ * N_ * 4 + (size_t)B_ * NOUT * 4;
  if (ws_size >= need) {
    float* sx = (float*)d_ws;
    float* sy = sx + (size_t)B_ * N_;
    float* sz = sy + (size_t)B_ * N_;
    int*   so = (int*)(sz + (size_t)B_ * N_);
    int*   sel = so + (size_t)B_ * N_;
    hipLaunchKernelGGL(sort_kernel, dim3(B_), dim3(1024), 0, stream,
                       pcd_x, sx, sy, sz, so);
    hipLaunchKernelGGL(fps_fast_kernel, dim3(B_), dim3(1024), 0, stream,
                       pcd_x, sx, sy, sz, so, sel, out_c);
    hipLaunchKernelGGL(proj_kernel, dim3(B_ * NOUT / RPB), dim3(TPB_PROJ), 0, stream,
                       tgt, pcd_v, W, bias, sel, out_f, out_v);
  } else {
    int* sel = (int*)d_ws;
    hipLaunchKernelGGL(fps_brute_kernel, dim3(B_), dim3(TPB_FPS), 0, stream,
                       pcd_x, sel, out_c);
    hipLaunchKernelGGL(proj_kernel, dim3(B_ * NOUT / RPB), dim3(TPB_PROJ), 0, stream,
                       tgt, pcd_v, W, bias, sel, out_f, out_v);
  }
}

// Round 6
// 1920.407 us; speedup vs baseline: 1.2025x; 1.2025x over previous
//
#include <hip/hip_runtime.h>

// Problem constants (from reference)
constexpr int B_   = 4;
constexpr int N_   = 16384;
constexpr int NOUT = 1170;   // 16384 // 14
constexpr int D_   = 128;
constexpr int O_   = 256;

typedef float f32x2 __attribute__((ext_vector_type(2)));
typedef unsigned long long u64;

// DPP fmax step (validated R4/R5: absmax=0 with this chain).
template <int CTRL>
__device__ __forceinline__ float dpp_fmax(float x) {
  int yi = __builtin_amdgcn_update_dpp(__float_as_int(x), __float_as_int(x),
                                       CTRL, 0xF, 0xF, false);
  return fmaxf(x, __int_as_float(yi));
}

// ---------------- FPS kernel ----------------
// One block per batch, 512 threads x 32 points, CONSECUTIVE ownership
// (thread t owns [t*32, t*32+32) so lane order == index order at every
// reduce tier -> np first-max tie semantics).
// waves_per_eu(2,2): 8 waves/CU = 2/SIMD -> 256-VGPR budget; the coord+dm
// arrays (128 VGPRs) are pinned live each iteration by an empty asm that
// redefines them (defeats the load-sinking that left VGPR_Count at
// 48/88/92/56/60 in rounds 1-5 and re-fetched 192KB/step from cache).
// Reduce: in-wave DPP max -> ballot -> winner lane ds_write_b64 {val,idx}
// -> ONE barrier -> lane-parallel 8-entry DPP reduce -> readlane idx ->
// uniform scalar coord load. No u64 tree (was ~55 instr/thread).
constexpr int TPB_FPS = 512;
constexpr int PPT   = N_ / TPB_FPS;  // 32 points per thread
constexpr int NPAIR = PPT / 2;       // 16 f32x2 pairs
constexpr int NW    = TPB_FPS / 64;  // 8 waves

__global__ __launch_bounds__(TPB_FPS)
__attribute__((amdgpu_waves_per_eu(2, 2)))
void fps_kernel(const float* __restrict__ pcd_x,
                int* __restrict__ sel,        // [B, NOUT] (workspace)
                float* __restrict__ out_c) {  // query_c [B, NOUT, 3]
  const int b = blockIdx.x, t = threadIdx.x;
  const float* __restrict__ P = pcd_x + (size_t)b * N_ * 3;
  const int base = t * PPT;  // consecutive ownership
  const int lane = t & 63;

  f32x2 x[NPAIR], y[NPAIR], z[NPAIR], dm[NPAIR];
#pragma unroll
  for (int k = 0; k < NPAIR; ++k) {
    const int p0 = base + 2 * k;
    x[k]  = f32x2{P[p0 * 3 + 0], P[p0 * 3 + 3]};
    y[k]  = f32x2{P[p0 * 3 + 1], P[p0 * 3 + 4]};
    z[k]  = f32x2{P[p0 * 3 + 2], P[p0 * 3 + 5]};
    dm[k] = f32x2{1e10f, 1e10f};
  }

  __shared__ float2 s_pair[2][NW];  // {wave max, idx bits}, parity-buffered

  float lx = P[0], ly = P[1], lz = P[2];
  if (t == 0) {
    sel[b * NOUT + 0] = 0;
    out_c[((size_t)b * NOUT + 0) * 3 + 0] = lx;
    out_c[((size_t)b * NOUT + 0) * 3 + 1] = ly;
    out_c[((size_t)b * NOUT + 0) * 3 + 2] = lz;
  }

  for (int step = 1; step < NOUT; ++step) {
    const int par = step & 1;

    // Liveness pin: redefining the arrays every iteration makes sinking the
    // original global loads into the loop illegal, and spilling would cost a
    // 128-reg reload per iter -> RA keeps them resident (budget 256).
    asm volatile("" : "+v"(x[0]), "+v"(x[1]), "+v"(x[2]), "+v"(x[3]),
                      "+v"(x[4]), "+v"(x[5]), "+v"(x[6]), "+v"(x[7]),
                      "+v"(x[8]), "+v"(x[9]), "+v"(x[10]), "+v"(x[11]),
                      "+v"(x[12]), "+v"(x[13]), "+v"(x[14]), "+v"(x[15]));
    asm volatile("" : "+v"(y[0]), "+v"(y[1]), "+v"(y[2]), "+v"(y[3]),
                      "+v"(y[4]), "+v"(y[5]), "+v"(y[6]), "+v"(y[7]),
                      "+v"(y[8]), "+v"(y[9]), "+v"(y[10]), "+v"(y[11]),
                      "+v"(y[12]), "+v"(y[13]), "+v"(y[14]), "+v"(y[15]));
    asm volatile("" : "+v"(z[0]), "+v"(z[1]), "+v"(z[2]), "+v"(z[3]),
                      "+v"(z[4]), "+v"(z[5]), "+v"(z[6]), "+v"(z[7]),
                      "+v"(z[8]), "+v"(z[9]), "+v"(z[10]), "+v"(z[11]),
                      "+v"(z[12]), "+v"(z[13]), "+v"(z[14]), "+v"(z[15]));

    const f32x2 lxx = {lx, lx}, lyy = {ly, ly}, lzz = {lz, lz};
    f32x2 bv2 = {-1.0f, -1.0f};
    {
#pragma clang fp contract(off)
#pragma unroll
      for (int k = 0; k < NPAIR; ++k) {
        // EXACT np order per component: ((dx*dx + dy*dy) + dz*dz), no FMA
        const f32x2 dx = x[k] - lxx;
        const f32x2 dy = y[k] - lyy;
        const f32x2 dz = z[k] - lzz;
        const f32x2 s  = (dx * dx + dy * dy) + dz * dz;
        f32x2 nd;
        nd.x = fminf(dm[k].x, s.x);
        nd.y = fminf(dm[k].y, s.y);
        dm[k] = nd;
        bv2.x = fmaxf(bv2.x, nd.x);
        bv2.y = fmaxf(bv2.y, nd.y);
      }
    }
    const float bv = fmaxf(bv2.x, bv2.y);

    // in-wave DPP max (lane 63 holds it) -> SGPR broadcast
    float wm = bv;
    wm = dpp_fmax<0xB1>(wm);   // quad xor1
    wm = dpp_fmax<0x4E>(wm);   // quad xor2
    wm = dpp_fmax<0x141>(wm);  // row_half_mirror (8)
    wm = dpp_fmax<0x140>(wm);  // row_mirror (16)
    wm = dpp_fmax<0x142>(wm);  // row_bcast15
    wm = dpp_fmax<0x143>(wm);  // row_bcast31
    const float wmax =
        __int_as_float(__builtin_amdgcn_readlane(__float_as_int(wm), 63));

    // in-thread first-max index (descending scan: last write = smallest j)
    int bi = 0;
#pragma unroll
    for (int k = NPAIR - 1; k >= 0; --k) {
      if (dm[k].y == bv) bi = base + 2 * k + 1;
      if (dm[k].x == bv) bi = base + 2 * k;
    }

    // first achieving lane = smallest index range (consecutive ownership)
    const u64 mask = __ballot(bv == wmax);
    const int flane = __builtin_ctzll(mask);
    if (lane == flane) {
      float2 pr;
      pr.x = wmax;                  // == bv on this lane
      pr.y = __int_as_float(bi);
      s_pair[par][t >> 6] = pr;     // one ds_write_b64 per wave
    }
    __syncthreads();  // the only barrier per step

    // lane-parallel cross-wave reduce: lane reads entry (lane&7); 3 DPP
    // steps give every lane the max over all 8; first matching lane id =
    // first (= min-index) wave.
    const float2 e = s_pair[par][lane & (NW - 1)];
    float gv = e.x;
    gv = dpp_fmax<0xB1>(gv);
    gv = dpp_fmax<0x4E>(gv);
    gv = dpp_fmax<0x141>(gv);
    const u64 m2 = __ballot(e.x == gv);
    const int ww = __builtin_ctzll(m2);  // in [0,8): winner wave id
    int ri = __builtin_amdgcn_readlane(__float_as_int(e.y), ww);

    // ri is SGPR-uniform -> scalar coord loads
    lx = P[ri * 3 + 0];
    ly = P[ri * 3 + 1];
    lz = P[ri * 3 + 2];
    if (t == 0) {
      sel[b * NOUT + step] = ri;
      out_c[((size_t)b * NOUT + step) * 3 + 0] = lx;
      out_c[((size_t)b * NOUT + step) * 3 + 1] = ly;
      out_c[((size_t)b * NOUT + step) * 3 + 2] = lz;
    }
  }
}

// ---------------- projection + gathers ----------------
constexpr int TPB_PROJ = 256;
constexpr int RPB = 4;

__global__ __launch_bounds__(TPB_PROJ)
void proj_kernel(const float* __restrict__ tgt,
                 const float* __restrict__ pcd_v,
                 const float* __restrict__ W,
                 const float* __restrict__ bias,
                 const int* __restrict__ sel,
                 float* __restrict__ out_f,    // [B*NOUT, 256]
                 float* __restrict__ out_v) {  // [B*NOUT, 9]
  const int t = threadIdx.x;
  const int row0 = blockIdx.x * RPB;
  __shared__ float sA[RPB * D_];
  __shared__ int   sIdx[RPB];
  if (t < RPB) {
    const int row = row0 + t;
    const int b = row / NOUT;
    sIdx[t] = b * N_ + sel[row];
  }
  __syncthreads();
#pragma unroll
  for (int l = 0; l < RPB * D_ / TPB_PROJ; ++l) {
    const int e = t + l * TPB_PROJ;
    const int r = e >> 7, k = e & (D_ - 1);
    sA[e] = tgt[(size_t)sIdx[r] * D_ + k];
  }
  __syncthreads();
  float acc0 = 0.f, acc1 = 0.f, acc2 = 0.f, acc3 = 0.f;
#pragma unroll 8
  for (int k = 0; k < D_; ++k) {
    const float w = W[k * O_ + t];
    acc0 = fmaf(sA[0 * D_ + k], w, acc0);
    acc1 = fmaf(sA[1 * D_ + k], w, acc1);
    acc2 = fmaf(sA[2 * D_ + k], w, acc2);
    acc3 = fmaf(sA[3 * D_ + k], w, acc3);
  }
  const float bb = bias[t];
  out_f[(size_t)(row0 + 0) * O_ + t] = acc0 + bb;
  out_f[(size_t)(row0 + 1) * O_ + t] = acc1 + bb;
  out_f[(size_t)(row0 + 2) * O_ + t] = acc2 + bb;
  out_f[(size_t)(row0 + 3) * O_ + t] = acc3 + bb;
  if (t < RPB * 9) {
    const int r = t / 9, e = t - r * 9;
    out_v[(size_t)(row0 + r) * 9 + e] = pcd_v[(size_t)sIdx[r] * 9 + e];
  }
}

extern "C" void kernel_launch(void* const* d_in, const int* in_sizes, int n_in,
                              void* d_out, int out_size, void* d_ws, size_t ws_size,
                              hipStream_t stream) {
  const float* tgt   = (const float*)d_in[0];  // [4,16384,128]
  const float* pcd_x = (const float*)d_in[1];  // [4,16384,3]
  const float* pcd_v = (const float*)d_in[2];  // [4,16384,3,3]
  const float* W     = (const float*)d_in[3];  // [128,256]
  const float* bias  = (const float*)d_in[4];  // [256]

  float* out   = (float*)d_out;
  float* out_f = out;                                   // [4,1170,256]
  float* out_c = out + (size_t)B_ * NOUT * O_;          // [4,1170,3]
  float* out_v = out_c + (size_t)B_ * NOUT * 3;         // [4,1170,3,3]

  int* sel = (int*)d_ws;  // [4,1170] int32

  hipLaunchKernelGGL(fps_kernel, dim3(B_), dim3(TPB_FPS), 0, stream,
                     pcd_x, sel, out_c);
  hipLaunchKernelGGL(proj_kernel, dim3(B_ * NOUT / RPB), dim3(TPB_PROJ), 0, stream,
                     tgt, pcd_v, W, bias, sel, out_f, out_v);
}